// Round 5
// baseline (512.046 us; speedup 1.0000x reference)
//
#include <hip/hip_runtime.h>

#define D 64
#define K 1024
#define NTOK (32 * 4096)        // 131072 tokens
#define TPB 256                 // 4 waves, 256 tokens per block
#define TILE 32                 // codes per inner tile
#define NTILE (K / TILE)        // 32

#define Q_ELEMS ((size_t)NTOK * D)
#define OH_ELEMS ((size_t)NTOK * K)

// ||e_k||^2 -> d_ws[k]; d-ascending fmaf chain (matches distance epilogue use)
__global__ void e2_kernel(const float* __restrict__ E, float* __restrict__ e2g) {
    int k = blockIdx.x * 256 + threadIdx.x;
    float s = 0.f;
    #pragma unroll
    for (int d = 0; d < D; ++d) {
        float v = E[d * K + k];
        s = fmaf(v, v, s);
    }
    e2g[k] = s;
}

__global__ __launch_bounds__(TPB, 2) void vq_kernel(
    const float* __restrict__ X,    // [NTOK, D]
    const float* __restrict__ E,    // [D, K]
    const float* __restrict__ e2g,  // [K]
    float* __restrict__ qout,       // [NTOK, D]
    float* __restrict__ oneh,       // [NTOK, K]
    float* __restrict__ idxout)     // [NTOK]
{
    // x transposed: xT[d*256 + (t ^ (d&31))]. XOR swizzle -> conflict-free
    // reads (64 lanes, consecutive t, XOR const) and ~2-way writes. 64 KB.
    __shared__ float xT[D * 256];

    const int tid = threadIdx.x;
    const size_t tokBase = (size_t)blockIdx.x * TPB;

    // --- stage X tile (coalesced float4) -> LDS transposed+swizzled ---
    {
        const float4* xp = reinterpret_cast<const float4*>(X + tokBase * D);
        #pragma unroll
        for (int it = 0; it < 16; ++it) {
            int f = it * 256 + tid;          // f4 index in 256x64 tile
            float4 v = xp[f];
            int t  = f >> 4;                 // local token
            int d0 = (f & 15) * 4;
            xT[(d0 + 0) * 256 + (t ^ ((d0 + 0) & 31))] = v.x;
            xT[(d0 + 1) * 256 + (t ^ ((d0 + 1) & 31))] = v.y;
            xT[(d0 + 2) * 256 + (t ^ ((d0 + 2) & 31))] = v.z;
            xT[(d0 + 3) * 256 + (t ^ ((d0 + 3) & 31))] = v.w;
        }
    }
    __syncthreads();

    // --- full-K argmin; per-code math bit-identical to R1-R4 ---
    float best = 3.4e38f;
    int   bidx = 0;
    float4* ohz = reinterpret_cast<float4*>(oneh + tokBase * K);
    const float4 z = make_float4(0.f, 0.f, 0.f, 0.f);

    #pragma unroll 1
    for (int tile = 0; tile < NTILE; ++tile) {
        const int t0 = tile * TILE;
        float acc[TILE];
        #pragma unroll
        for (int j = 0; j < TILE; ++j) acc[j] = 0.f;

        #pragma unroll
        for (int d = 0; d < D; ++d) {
            float xv = xT[d * 256 + (tid ^ (d & 31))];   // 1 ds_read per 32 FMA
            const float* ep = E + d * K + t0;             // wave-uniform -> s_load
            #pragma unroll
            for (int j = 0; j < TILE; ++j)
                acc[j] = fmaf(xv, ep[j], acc[j]);
        }

        const float* e2p = e2g + t0;                      // uniform -> s_load
        #pragma unroll
        for (int j = 0; j < TILE; ++j) {
            float dist = fmaf(-2.f, acc[j], e2p[j]);
            if (dist < best) { best = dist; bidx = t0 + j; }  // strict <: lowest idx
        }

        // one-hot zero-stream interleaved with compute (fire-and-forget)
        #pragma unroll
        for (int zi = 0; zi < 8; ++zi)
            ohz[tile * 2048 + zi * 256 + tid] = z;
    }

    // --- quantized (STE: x + (q - x)) + index, own token ---
    {
        const size_t tok = tokBase + tid;
        float q[D];
        const float* ec = E + bidx;
        #pragma unroll
        for (int d = 0; d < D; ++d) q[d] = ec[d * K];

        float* qp = qout + tok * D;
        #pragma unroll
        for (int j = 0; j < D / 4; ++j) {
            float4 v;
            float x0 = xT[(4 * j + 0) * 256 + (tid ^ ((4 * j + 0) & 31))];
            float x1 = xT[(4 * j + 1) * 256 + (tid ^ ((4 * j + 1) & 31))];
            float x2 = xT[(4 * j + 2) * 256 + (tid ^ ((4 * j + 2) & 31))];
            float x3 = xT[(4 * j + 3) * 256 + (tid ^ ((4 * j + 3) & 31))];
            v.x = x0 + (q[4 * j + 0] - x0);
            v.y = x1 + (q[4 * j + 1] - x1);
            v.z = x2 + (q[4 * j + 2] - x2);
            v.w = x3 + (q[4 * j + 3] - x3);
            *reinterpret_cast<float4*>(qp + 4 * j) = v;
        }
        idxout[tok] = (float)bidx;
    }

    // barrier drains all zero-stores (vmcnt(0) before s_barrier) -> safe to scatter 1s
    __syncthreads();
    oneh[(tokBase + tid) * (size_t)K + bidx] = 1.0f;
}

extern "C" void kernel_launch(void* const* d_in, const int* in_sizes, int n_in,
                              void* d_out, int out_size, void* d_ws, size_t ws_size,
                              hipStream_t stream) {
    const float* X = (const float*)d_in[0];
    const float* E = (const float*)d_in[1];

    float* qout   = (float*)d_out;
    float* oneh   = qout + Q_ELEMS;
    float* idxout = oneh + OH_ELEMS;
    float* e2g    = (float*)d_ws;   // 4 KB scratch

    e2_kernel<<<K / 256, 256, 0, stream>>>(E, e2g);
    vq_kernel<<<NTOK / TPB, TPB, 0, stream>>>(X, E, e2g, qout, oneh, idxout);
}

// Round 6
// 465.610 us; speedup vs baseline: 1.0997x; 1.0997x over previous
//
#include <hip/hip_runtime.h>

#define D 64
#define K 1024
#define NTOK (32 * 4096)        // 131072 tokens
#define Q_ELEMS ((size_t)NTOK * D)
#define OH_ELEMS ((size_t)NTOK * K)

typedef short bf16x8 __attribute__((ext_vector_type(8)));
typedef float f32x4 __attribute__((ext_vector_type(4)));

// workspace layout (bytes)
#define WS_ETF_OFF 4096                          // float  Et[K][D]  (exact transposed E, 256KB)
#define WS_ETH_OFF (4096 + 262144)               // ushort EtHi[K][D] bf16 (128KB)
#define WS_ETL_OFF (4096 + 262144 + 131072)      // ushort EtLo[K][D] bf16 (128KB)
#define WS_NEED    (4096 + 262144 + 131072 + 131072)

__device__ __forceinline__ unsigned short f2bf(float f) {   // RNE f32->bf16
    unsigned u = __float_as_uint(f);
    unsigned r = u + 0x7FFFu + ((u >> 16) & 1u);
    return (unsigned short)(r >> 16);
}
__device__ __forceinline__ float bf2f(unsigned short h) {
    return __uint_as_float(((unsigned)h) << 16);
}

// ---- prep: e2 (exact, d-ascending fmaf chain), transposed E (f32 + bf16 hi/lo) ----
__global__ void prep_kernel(const float* __restrict__ E, float* __restrict__ ws) {
    int k = blockIdx.x * 256 + threadIdx.x;
    float* e2 = ws;
    float* etf = (float*)((char*)ws + WS_ETF_OFF);
    unsigned short* eth = (unsigned short*)((char*)ws + WS_ETH_OFF);
    unsigned short* etl = (unsigned short*)((char*)ws + WS_ETL_OFF);
    float s = 0.f;
    #pragma unroll
    for (int d = 0; d < D; ++d) {
        float v = E[d * K + k];
        s = fmaf(v, v, s);
        etf[k * D + d] = v;
        unsigned short h = f2bf(v);
        eth[k * D + d] = h;
        etl[k * D + d] = f2bf(v - bf2f(h));
    }
    e2[k] = s;
}

// ---- exact rescore (bit-identical to R1 chain): full wave scans all K for one token ----
__device__ __attribute__((noinline)) int rescore_token(
    const float* __restrict__ X, const float* __restrict__ E,
    const float* __restrict__ e2g, int tok, int tid)
{
    const float* xr = X + (size_t)tok * D;
    float bestv = 3.4e38f; int besti = 0;
    #pragma unroll 1
    for (int sb = 0; sb < 2; ++sb) {
        const int k0 = tid * 16 + sb * 8;     // lane's 8 codes, ascending
        float dot[8] = {0.f,0.f,0.f,0.f,0.f,0.f,0.f,0.f};
        #pragma unroll 1
        for (int db = 0; db < 4; ++db) {
            float4 xc0 = *reinterpret_cast<const float4*>(xr + db * 16 + 0);
            float4 xc1 = *reinterpret_cast<const float4*>(xr + db * 16 + 4);
            float4 xc2 = *reinterpret_cast<const float4*>(xr + db * 16 + 8);
            float4 xc3 = *reinterpret_cast<const float4*>(xr + db * 16 + 12);
            float xs[16] = {xc0.x,xc0.y,xc0.z,xc0.w, xc1.x,xc1.y,xc1.z,xc1.w,
                            xc2.x,xc2.y,xc2.z,xc2.w, xc3.x,xc3.y,xc3.z,xc3.w};
            #pragma unroll
            for (int dd = 0; dd < 16; ++dd) {             // d ascending => same chain as R1
                const int d = db * 16 + dd;
                float4 e0 = *reinterpret_cast<const float4*>(E + (size_t)d * K + k0);
                float4 e1 = *reinterpret_cast<const float4*>(E + (size_t)d * K + k0 + 4);
                dot[0] = fmaf(xs[dd], e0.x, dot[0]); dot[1] = fmaf(xs[dd], e0.y, dot[1]);
                dot[2] = fmaf(xs[dd], e0.z, dot[2]); dot[3] = fmaf(xs[dd], e0.w, dot[3]);
                dot[4] = fmaf(xs[dd], e1.x, dot[4]); dot[5] = fmaf(xs[dd], e1.y, dot[5]);
                dot[6] = fmaf(xs[dd], e1.z, dot[6]); dot[7] = fmaf(xs[dd], e1.w, dot[7]);
            }
        }
        float4 ez0 = *reinterpret_cast<const float4*>(e2g + k0);
        float4 ez1 = *reinterpret_cast<const float4*>(e2g + k0 + 4);
        float ezs[8] = {ez0.x,ez0.y,ez0.z,ez0.w, ez1.x,ez1.y,ez1.z,ez1.w};
        #pragma unroll
        for (int j = 0; j < 8; ++j) {
            float dist = fmaf(-2.f, dot[j], ezs[j]);
            if (dist < bestv) { bestv = dist; besti = k0 + j; }   // strict <: lowest idx
        }
    }
    // full-wave lexicographic (val, idx) reduce == first-min over ascending K
    #pragma unroll
    for (int mm = 1; mm <= 32; mm <<= 1) {
        float ob = __shfl_xor(bestv, mm, 64);
        int   oi = __shfl_xor(besti, mm, 64);
        bool take = (ob < bestv) || (ob == bestv && oi < besti);
        bestv = take ? ob : bestv;
        besti = take ? oi : besti;
    }
    return besti;
}

// ---- main: 1 wave/block, 16 tokens/wave, MFMA bf16x3 distances + margin-guarded argmin ----
__global__ __launch_bounds__(64, 4) void vq_mfma_kernel(
    const float* __restrict__ X,
    const float* __restrict__ E,
    const float* __restrict__ ws_f,
    float* __restrict__ qout,
    float* __restrict__ oneh,
    float* __restrict__ idxout)
{
    const int tid = threadIdx.x;
    const int lane15 = tid & 15;
    const int g = tid >> 4;                     // 0..3
    const int tokbase = blockIdx.x * 16;

    const float* e2g = ws_f;
    const float* etf = (const float*)((const char*)ws_f + WS_ETF_OFF);
    const unsigned short* eth = (const unsigned short*)((const char*)ws_f + WS_ETH_OFF);
    const unsigned short* etl = (const unsigned short*)((const char*)ws_f + WS_ETL_OFF);

    // A fragments: lane holds token row (lane&15), k-elems (g*8..g*8+7) per k-slice.
    // Same (g,j)->k map used for B below => dot correct for any symmetric HW layout.
    bf16x8 ah[2], al[2];
    {
        const float* xr = X + (size_t)(tokbase + lane15) * D + g * 8;
        #pragma unroll
        for (int ks = 0; ks < 2; ++ks) {
            float4 v0 = *reinterpret_cast<const float4*>(xr + ks * 32);
            float4 v1 = *reinterpret_cast<const float4*>(xr + ks * 32 + 4);
            float xv[8] = {v0.x,v0.y,v0.z,v0.w, v1.x,v1.y,v1.z,v1.w};
            #pragma unroll
            for (int j = 0; j < 8; ++j) {
                unsigned short h = f2bf(xv[j]);
                ah[ks][j] = (short)h;
                al[ks][j] = (short)f2bf(xv[j] - bf2f(h));
            }
        }
    }

    float bb[4] = {3.4e38f,3.4e38f,3.4e38f,3.4e38f};
    float b2[4] = {3.4e38f,3.4e38f,3.4e38f,3.4e38f};
    int   bi[4] = {0,0,0,0};

    #pragma unroll 1
    for (int cbase = 0; cbase < K; cbase += 64) {
        #pragma unroll
        for (int ct = 0; ct < 4; ++ct) {
            const int code = cbase + ct * 16 + lane15;
            const unsigned short* bhp = eth + (size_t)code * D + g * 8;
            const unsigned short* blp = etl + (size_t)code * D + g * 8;
            f32x4 acc = {0.f, 0.f, 0.f, 0.f};
            #pragma unroll
            for (int ks = 0; ks < 2; ++ks) {
                bf16x8 bh = *reinterpret_cast<const bf16x8*>(bhp + ks * 32);
                bf16x8 bl = *reinterpret_cast<const bf16x8*>(blp + ks * 32);
                acc = __builtin_amdgcn_mfma_f32_16x16x32_bf16(ah[ks], bh, acc, 0, 0, 0);
                acc = __builtin_amdgcn_mfma_f32_16x16x32_bf16(ah[ks], bl, acc, 0, 0, 0);
                acc = __builtin_amdgcn_mfma_f32_16x16x32_bf16(al[ks], bh, acc, 0, 0, 0);
            }
            const float e2v = e2g[code];
            #pragma unroll
            for (int r = 0; r < 4; ++r) {       // C/D: row=(g*4+r)=token, col=lane15=code
                float dist = fmaf(-2.f, acc[r], e2v);
                b2[r] = fminf(b2[r], fmaxf(bb[r], dist));
                if (dist < bb[r]) { bb[r] = dist; bi[r] = code; }
            }
        }
    }

    // one-hot zeros early (overlap with reduce/rescore); 16 rows x 1024 f32
    {
        float4* ohb = reinterpret_cast<float4*>(oneh + (size_t)tokbase * K);
        const float4 z = make_float4(0.f, 0.f, 0.f, 0.f);
        #pragma unroll
        for (int it = 0; it < 64; ++it) ohb[it * 64 + tid] = z;
    }

    // reduce best/best2 across the 16 lanes sharing token rows (xor 1,2,4,8)
    #pragma unroll
    for (int m = 1; m <= 8; m <<= 1) {
        #pragma unroll
        for (int r = 0; r < 4; ++r) {
            float ob = __shfl_xor(bb[r], m, 64);
            float o2 = __shfl_xor(b2[r], m, 64);
            int   oi = __shfl_xor(bi[r], m, 64);
            float nb2 = fminf(fminf(b2[r], o2), fmaxf(bb[r], ob));
            bool take = (ob < bb[r]) || (ob == bb[r] && oi < bi[r]);
            bb[r] = take ? ob : bb[r];
            bi[r] = take ? oi : bi[r];
            b2[r] = nb2;
        }
    }

    // margin-guarded exact rescore (tau = 0.125 >> 2x bf16x3 error bound ~0.01)
    #pragma unroll
    for (int r = 0; r < 4; ++r) {
        bool flag = (b2[r] - bb[r]) < 0.125f;
        unsigned long long m = __ballot(flag);
        if (m) {
            #pragma unroll
            for (int gg = 0; gg < 4; ++gg) {
                if ((m >> (gg * 16)) & 1ULL) {          // wave-uniform branch
                    int ei = rescore_token(X, E, e2g, tokbase + gg * 4 + r, tid);
                    if (g == gg) bi[r] = ei;
                }
            }
        }
    }

    __builtin_amdgcn_s_waitcnt(0);   // drain one-hot zeros before scattering 1s

    // epilogue: per token -> quantized row (exact f32), index, one-hot 1
    #pragma unroll
    for (int t = 0; t < 16; ++t) {
        int fi = __shfl(bi[t & 3], (t >> 2) * 16, 64);
        const size_t tok = (size_t)tokbase + t;
        float q = etf[(size_t)fi * D + tid];     // exact copy of E[tid][fi]
        float x = X[tok * D + tid];
        qout[tok * D + tid] = x + (q - x);       // STE, same expr as reference
        if (tid == 0) idxout[tok] = (float)fi;
        if (tid == t) oneh[tok * (size_t)K + fi] = 1.0f;
    }
}

// ---- fallback (R1, proven, no workspace) in case ws_size is too small ----
__global__ __launch_bounds__(256, 2) void vq_fallback_kernel(
    const float* __restrict__ X, const float* __restrict__ E,
    float* __restrict__ qout, float* __restrict__ oneh, float* __restrict__ idxout)
{
    __shared__ float e2s[K];
    __shared__ int   idxs[256];
    const int tid = threadIdx.x;
    const int tok = blockIdx.x * 256 + tid;
    for (int k = tid; k < K; k += 256) {
        float s = 0.f;
        #pragma unroll
        for (int d = 0; d < D; ++d) { float v = E[d * K + k]; s = fmaf(v, v, s); }
        e2s[k] = s;
    }
    __syncthreads();
    float x[D];
    {
        const float* xp = X + (size_t)tok * D;
        #pragma unroll
        for (int j = 0; j < D / 4; ++j) {
            float4 v = *reinterpret_cast<const float4*>(xp + 4 * j);
            x[4*j+0]=v.x; x[4*j+1]=v.y; x[4*j+2]=v.z; x[4*j+3]=v.w;
        }
    }
    float best = 3.4e38f; int bidx = 0;
    for (int t0 = 0; t0 < K; t0 += 16) {
        float acc[16];
        #pragma unroll
        for (int j = 0; j < 16; ++j) acc[j] = 0.f;
        #pragma unroll
        for (int d = 0; d < D; ++d) {
            const float* ep = E + d * K + t0;
            #pragma unroll
            for (int j = 0; j < 16; ++j) acc[j] = fmaf(x[d], ep[j], acc[j]);
        }
        #pragma unroll
        for (int j = 0; j < 16; ++j) {
            float dist = fmaf(-2.f, acc[j], e2s[t0 + j]);
            if (dist < best) { best = dist; bidx = t0 + j; }
        }
    }
    idxs[tid] = bidx;
    {
        float q[D];
        const float* ec = E + bidx;
        #pragma unroll
        for (int d = 0; d < D; ++d) q[d] = ec[d * K];
        float* qp = qout + (size_t)tok * D;
        #pragma unroll
        for (int j = 0; j < D / 4; ++j) {
            float4 v;
            v.x = x[4*j+0] + (q[4*j+0] - x[4*j+0]);
            v.y = x[4*j+1] + (q[4*j+1] - x[4*j+1]);
            v.z = x[4*j+2] + (q[4*j+2] - x[4*j+2]);
            v.w = x[4*j+3] + (q[4*j+3] - x[4*j+3]);
            *reinterpret_cast<float4*>(qp + 4 * j) = v;
        }
    }
    idxout[tok] = (float)bidx;
    __syncthreads();
    {
        float4* base = reinterpret_cast<float4*>(oneh + (size_t)blockIdx.x * 256 * K);
        for (int i = tid; i < 256 * K / 4; i += 256) {
            int row = i >> 8, c4 = (i & 255) * 4, id = idxs[row];
            float4 v;
            v.x = (id == c4 + 0) ? 1.f : 0.f;
            v.y = (id == c4 + 1) ? 1.f : 0.f;
            v.z = (id == c4 + 2) ? 1.f : 0.f;
            v.w = (id == c4 + 3) ? 1.f : 0.f;
            base[i] = v;
        }
    }
}

extern "C" void kernel_launch(void* const* d_in, const int* in_sizes, int n_in,
                              void* d_out, int out_size, void* d_ws, size_t ws_size,
                              hipStream_t stream) {
    const float* X = (const float*)d_in[0];
    const float* E = (const float*)d_in[1];
    float* qout   = (float*)d_out;
    float* oneh   = qout + Q_ELEMS;
    float* idxout = oneh + OH_ELEMS;

    if (ws_size >= (size_t)WS_NEED) {
        float* ws = (float*)d_ws;
        prep_kernel<<<K / 256, 256, 0, stream>>>(E, ws);
        vq_mfma_kernel<<<NTOK / 16, 64, 0, stream>>>(X, E, ws, qout, oneh, idxout);
    } else {
        vq_fallback_kernel<<<NTOK / 256, 256, 0, stream>>>(X, E, qout, oneh, idxout);
    }
}

// Round 7
// 325.099 us; speedup vs baseline: 1.5750x; 1.4322x over previous
//
#include <hip/hip_runtime.h>

#define D 64
#define K 1024
#define NTOK (32 * 4096)        // 131072 tokens
#define Q_ELEMS ((size_t)NTOK * D)
#define OH_ELEMS ((size_t)NTOK * K)

typedef short bf16x8 __attribute__((ext_vector_type(8)));
typedef float f32x4 __attribute__((ext_vector_type(4)));

// ws layout (bytes): e2[1024] f32 | etf[K][D] f32 | ethF frags | etlF frags
#define WS_ETF_OFF 4096                          // 256 KB exact transposed E
#define WS_ETH_OFF (4096 + 262144)               // 128 KB bf16-hi fragments
#define WS_ETL_OFF (4096 + 262144 + 131072)      // 128 KB bf16-lo fragments
#define WS_NEED    (4096 + 262144 + 131072 + 131072)

__device__ __forceinline__ unsigned short f2bf(float f) {   // RNE f32->bf16
    unsigned u = __float_as_uint(f);
    unsigned r = u + 0x7FFFu + ((u >> 16) & 1u);
    return (unsigned short)(r >> 16);
}
__device__ __forceinline__ float bf2f(unsigned short h) {
    return __uint_as_float(((unsigned)h) << 16);
}

// ---- prep: e2 (exact, d-ascending chain), etf, and FRAGMENT-ORDERED bf16 tables.
// Frag slot for (tile,ct,ks, lane): idx = ((tile*4+ct)*2+ks)*64 + lane, 8 shorts each;
// lane = g*16+l15 holds dims d = ks*32 + g*8 + j  (identical mapping to proven R6).
__global__ void prep_kernel(const float* __restrict__ E, float* __restrict__ ws) {
    int k = blockIdx.x * 256 + threadIdx.x;      // code
    float* e2 = ws;
    float* etf = (float*)((char*)ws + WS_ETF_OFF);
    unsigned short* ethF = (unsigned short*)((char*)ws + WS_ETH_OFF);
    unsigned short* etlF = (unsigned short*)((char*)ws + WS_ETL_OFF);

    const int tile = k >> 6, ct = (k >> 4) & 3, l15 = k & 15;
    float s = 0.f;
    #pragma unroll
    for (int d = 0; d < D; ++d) {
        float v = E[d * K + k];
        s = fmaf(v, v, s);
        etf[k * D + d] = v;
        unsigned short h = f2bf(v);
        unsigned short l = f2bf(v - bf2f(h));
        const int ks = d >> 5, g = (d >> 3) & 3, j = d & 7;
        const int slot = (((tile * 4 + ct) * 2 + ks) * 64 + g * 16 + l15) * 8 + j;
        ethF[slot] = h;
        etlF[slot] = l;
    }
    e2[k] = s;
}

// ---- exact rescore (bit-identical R1 chain); lane = wave lane 0..63 ----
__device__ __attribute__((noinline)) int rescore_token(
    const float* __restrict__ X, const float* __restrict__ E,
    const float* __restrict__ e2g, int tok, int lane)
{
    const float* xr = X + (size_t)tok * D;
    float bestv = 3.4e38f; int besti = 0;
    #pragma unroll 1
    for (int sb = 0; sb < 2; ++sb) {
        const int k0 = lane * 16 + sb * 8;
        float dot[8] = {0.f,0.f,0.f,0.f,0.f,0.f,0.f,0.f};
        #pragma unroll 1
        for (int db = 0; db < 4; ++db) {
            float4 xc0 = *reinterpret_cast<const float4*>(xr + db * 16 + 0);
            float4 xc1 = *reinterpret_cast<const float4*>(xr + db * 16 + 4);
            float4 xc2 = *reinterpret_cast<const float4*>(xr + db * 16 + 8);
            float4 xc3 = *reinterpret_cast<const float4*>(xr + db * 16 + 12);
            float xs[16] = {xc0.x,xc0.y,xc0.z,xc0.w, xc1.x,xc1.y,xc1.z,xc1.w,
                            xc2.x,xc2.y,xc2.z,xc2.w, xc3.x,xc3.y,xc3.z,xc3.w};
            #pragma unroll
            for (int dd = 0; dd < 16; ++dd) {           // d ascending
                const int d = db * 16 + dd;
                float4 e0 = *reinterpret_cast<const float4*>(E + (size_t)d * K + k0);
                float4 e1 = *reinterpret_cast<const float4*>(E + (size_t)d * K + k0 + 4);
                dot[0] = fmaf(xs[dd], e0.x, dot[0]); dot[1] = fmaf(xs[dd], e0.y, dot[1]);
                dot[2] = fmaf(xs[dd], e0.z, dot[2]); dot[3] = fmaf(xs[dd], e0.w, dot[3]);
                dot[4] = fmaf(xs[dd], e1.x, dot[4]); dot[5] = fmaf(xs[dd], e1.y, dot[5]);
                dot[6] = fmaf(xs[dd], e1.z, dot[6]); dot[7] = fmaf(xs[dd], e1.w, dot[7]);
            }
        }
        float4 ez0 = *reinterpret_cast<const float4*>(e2g + k0);
        float4 ez1 = *reinterpret_cast<const float4*>(e2g + k0 + 4);
        float ezs[8] = {ez0.x,ez0.y,ez0.z,ez0.w, ez1.x,ez1.y,ez1.z,ez1.w};
        #pragma unroll
        for (int j = 0; j < 8; ++j) {
            float dist = fmaf(-2.f, dot[j], ezs[j]);
            if (dist < bestv) { bestv = dist; besti = k0 + j; }
        }
    }
    #pragma unroll
    for (int mm = 1; mm <= 32; mm <<= 1) {
        float ob = __shfl_xor(bestv, mm, 64);
        int   oi = __shfl_xor(besti, mm, 64);
        bool take = (ob < bestv) || (ob == bestv && oi < besti);
        bestv = take ? ob : bestv;
        besti = take ? oi : besti;
    }
    return besti;
}

// ---- main: 4 waves/block, 16 tokens/wave; MFMA bf16x3 + margin-guarded argmin ----
__global__ __launch_bounds__(256, 6) void vq_mfma_kernel(
    const float* __restrict__ X,
    const float* __restrict__ E,
    const float* __restrict__ ws_f,
    float* __restrict__ qout,
    float* __restrict__ oneh,   // pre-zeroed by hipMemsetAsync
    float* __restrict__ idxout)
{
    const int lane   = threadIdx.x & 63;
    const int wv     = threadIdx.x >> 6;          // wave 0..3
    const int lane15 = lane & 15;
    const int g      = lane >> 4;                 // 0..3
    const int tokbase = blockIdx.x * 64 + wv * 16;

    const float* e2g = ws_f;
    const float* etf = (const float*)((const char*)ws_f + WS_ETF_OFF);
    const bf16x8* ethF = (const bf16x8*)((const char*)ws_f + WS_ETH_OFF);
    const bf16x8* etlF = (const bf16x8*)((const char*)ws_f + WS_ETL_OFF);

    // A fragments (same mapping as proven R6)
    bf16x8 ah[2], al[2];
    {
        const float* xr = X + (size_t)(tokbase + lane15) * D + g * 8;
        #pragma unroll
        for (int ks = 0; ks < 2; ++ks) {
            float4 v0 = *reinterpret_cast<const float4*>(xr + ks * 32);
            float4 v1 = *reinterpret_cast<const float4*>(xr + ks * 32 + 4);
            float xv[8] = {v0.x,v0.y,v0.z,v0.w, v1.x,v1.y,v1.z,v1.w};
            #pragma unroll
            for (int j = 0; j < 8; ++j) {
                unsigned short h = f2bf(xv[j]);
                ah[ks][j] = (short)h;
                al[ks][j] = (short)f2bf(xv[j] - bf2f(h));
            }
        }
    }

    float bb[4] = {3.4e38f,3.4e38f,3.4e38f,3.4e38f};
    float b2[4] = {3.4e38f,3.4e38f,3.4e38f,3.4e38f};
    int   bi[4] = {0,0,0,0};

    #pragma unroll 1
    for (int tile = 0; tile < 16; ++tile) {
        #pragma unroll
        for (int ct = 0; ct < 4; ++ct) {
            const int code = tile * 64 + ct * 16 + lane15;
            f32x4 acc = {0.f, 0.f, 0.f, 0.f};
            #pragma unroll
            for (int ks = 0; ks < 2; ++ks) {
                // contiguous 1KB wave load: slot = (tile*8 + ct*2 + ks)*64 + lane
                const int slot = (tile * 8 + ct * 2 + ks) * 64 + lane;
                bf16x8 bh = ethF[slot];
                bf16x8 bl = etlF[slot];
                acc = __builtin_amdgcn_mfma_f32_16x16x32_bf16(ah[ks], bh, acc, 0, 0, 0);
                acc = __builtin_amdgcn_mfma_f32_16x16x32_bf16(ah[ks], bl, acc, 0, 0, 0);
                acc = __builtin_amdgcn_mfma_f32_16x16x32_bf16(al[ks], bh, acc, 0, 0, 0);
            }
            const float e2v = e2g[code];
            #pragma unroll
            for (int r = 0; r < 4; ++r) {   // C/D: col=lane15=code, row=g*4+r=token
                float dist = fmaf(-2.f, acc[r], e2v);
                b2[r] = fminf(b2[r], fmaxf(bb[r], dist));
                if (dist < bb[r]) { bb[r] = dist; bi[r] = code; }
            }
        }
    }

    // reduce best/best2 over the 16 lanes sharing each token row
    #pragma unroll
    for (int m = 1; m <= 8; m <<= 1) {
        #pragma unroll
        for (int r = 0; r < 4; ++r) {
            float ob = __shfl_xor(bb[r], m, 64);
            float o2 = __shfl_xor(b2[r], m, 64);
            int   oi = __shfl_xor(bi[r], m, 64);
            float nb2 = fminf(fminf(b2[r], o2), fmaxf(bb[r], ob));
            bool take = (ob < bb[r]) || (ob == bb[r] && oi < bi[r]);
            bb[r] = take ? ob : bb[r];
            bi[r] = take ? oi : bi[r];
            b2[r] = nb2;
        }
    }

    // margin-guarded exact rescore (tau = 0.125, proven R6)
    #pragma unroll
    for (int r = 0; r < 4; ++r) {
        bool flag = (b2[r] - bb[r]) < 0.125f;
        unsigned long long m = __ballot(flag);
        if (m) {
            #pragma unroll
            for (int gg = 0; gg < 4; ++gg) {
                if ((m >> (gg * 16)) & 1ULL) {
                    int ei = rescore_token(X, E, e2g, tokbase + gg * 4 + r, lane);
                    if (g == gg) bi[r] = ei;
                }
            }
        }
    }

    // epilogue: qout (exact f32), index, one-hot scatter (zeros via memset)
    #pragma unroll
    for (int t = 0; t < 16; ++t) {
        int fi = __shfl(bi[t & 3], (t >> 2) * 16, 64);
        const size_t tok = (size_t)tokbase + t;
        float q = etf[(size_t)fi * D + lane];
        float xv = X[tok * D + lane];
        qout[tok * D + lane] = xv + (q - xv);     // STE, same expr as reference
        if (lane == t) {
            idxout[tok] = (float)fi;
            oneh[tok * (size_t)K + fi] = 1.0f;
        }
    }
}

// ---- fallback (R1, proven) if workspace too small ----
__global__ __launch_bounds__(256, 2) void vq_fallback_kernel(
    const float* __restrict__ X, const float* __restrict__ E,
    float* __restrict__ qout, float* __restrict__ oneh, float* __restrict__ idxout)
{
    __shared__ float e2s[K];
    __shared__ int   idxs[256];
    const int tid = threadIdx.x;
    const int tok = blockIdx.x * 256 + tid;
    for (int k = tid; k < K; k += 256) {
        float s = 0.f;
        #pragma unroll
        for (int d = 0; d < D; ++d) { float v = E[d * K + k]; s = fmaf(v, v, s); }
        e2s[k] = s;
    }
    __syncthreads();
    float x[D];
    {
        const float* xp = X + (size_t)tok * D;
        #pragma unroll
        for (int j = 0; j < D / 4; ++j) {
            float4 v = *reinterpret_cast<const float4*>(xp + 4 * j);
            x[4*j+0]=v.x; x[4*j+1]=v.y; x[4*j+2]=v.z; x[4*j+3]=v.w;
        }
    }
    float best = 3.4e38f; int bidx = 0;
    for (int t0 = 0; t0 < K; t0 += 16) {
        float acc[16];
        #pragma unroll
        for (int j = 0; j < 16; ++j) acc[j] = 0.f;
        #pragma unroll
        for (int d = 0; d < D; ++d) {
            const float* ep = E + d * K + t0;
            #pragma unroll
            for (int j = 0; j < 16; ++j) acc[j] = fmaf(x[d], ep[j], acc[j]);
        }
        #pragma unroll
        for (int j = 0; j < 16; ++j) {
            float dist = fmaf(-2.f, acc[j], e2s[t0 + j]);
            if (dist < best) { best = dist; bidx = t0 + j; }
        }
    }
    idxs[tid] = bidx;
    {
        float q[D];
        const float* ec = E + bidx;
        #pragma unroll
        for (int d = 0; d < D; ++d) q[d] = ec[d * K];
        float* qp = qout + (size_t)tok * D;
        #pragma unroll
        for (int j = 0; j < D / 4; ++j) {
            float4 v;
            v.x = x[4*j+0] + (q[4*j+0] - x[4*j+0]);
            v.y = x[4*j+1] + (q[4*j+1] - x[4*j+1]);
            v.z = x[4*j+2] + (q[4*j+2] - x[4*j+2]);
            v.w = x[4*j+3] + (q[4*j+3] - x[4*j+3]);
            *reinterpret_cast<float4*>(qp + 4 * j) = v;
        }
    }
    idxout[tok] = (float)bidx;
    __syncthreads();
    {
        float4* base = reinterpret_cast<float4*>(oneh + (size_t)blockIdx.x * 256 * K);
        for (int i = tid; i < 256 * K / 4; i += 256) {
            int row = i >> 8, c4 = (i & 255) * 4, id = idxs[row];
            float4 v;
            v.x = (id == c4 + 0) ? 1.f : 0.f;
            v.y = (id == c4 + 1) ? 1.f : 0.f;
            v.z = (id == c4 + 2) ? 1.f : 0.f;
            v.w = (id == c4 + 3) ? 1.f : 0.f;
            base[i] = v;
        }
    }
}

extern "C" void kernel_launch(void* const* d_in, const int* in_sizes, int n_in,
                              void* d_out, int out_size, void* d_ws, size_t ws_size,
                              hipStream_t stream) {
    const float* X = (const float*)d_in[0];
    const float* E = (const float*)d_in[1];
    float* qout   = (float*)d_out;
    float* oneh   = qout + Q_ELEMS;
    float* idxout = oneh + OH_ELEMS;

    if (ws_size >= (size_t)WS_NEED) {
        float* ws = (float*)d_ws;
        // pure-write BW diagnostic + removes the 537MB store stream from the kernel
        hipMemsetAsync(oneh, 0, OH_ELEMS * sizeof(float), stream);
        prep_kernel<<<K / 256, 256, 0, stream>>>(E, ws);
        vq_mfma_kernel<<<NTOK / 64, 256, 0, stream>>>(X, E, ws, qout, oneh, idxout);
    } else {
        vq_fallback_kernel<<<NTOK / 256, 256, 0, stream>>>(X, E, qout, oneh, idxout);
    }
}

// Round 8
// 297.459 us; speedup vs baseline: 1.7214x; 1.0929x over previous
//
#include <hip/hip_runtime.h>

#define D 64
#define K 1024
#define NTOK (32 * 4096)        // 131072 tokens
#define Q_ELEMS ((size_t)NTOK * D)
#define OH_ELEMS ((size_t)NTOK * K)

typedef short bf16x8 __attribute__((ext_vector_type(8)));
typedef float f32x4 __attribute__((ext_vector_type(4)));

// ws layout (bytes): e2[1024] f32 | etf[K][D] f32 | ethF frags | etlF frags
#define WS_ETF_OFF 4096                          // 256 KB exact transposed E
#define WS_ETH_OFF (4096 + 262144)               // 128 KB bf16-hi fragments
#define WS_ETL_OFF (4096 + 262144 + 131072)      // 128 KB bf16-lo fragments
#define WS_NEED    (4096 + 262144 + 131072 + 131072)

__device__ __forceinline__ unsigned short f2bf(float f) {   // RNE f32->bf16
    unsigned u = __float_as_uint(f);
    unsigned r = u + 0x7FFFu + ((u >> 16) & 1u);
    return (unsigned short)(r >> 16);
}
__device__ __forceinline__ float bf2f(unsigned short h) {
    return __uint_as_float(((unsigned)h) << 16);
}

// ---- prep: e2 (exact, d-ascending chain), etf, FRAGMENT-ORDERED bf16 tables ----
// slot for (tile,ct,ks,lane): ((tile*4+ct)*2+ks)*64 + lane, 8 shorts each;
// lane = g*16+l15 holds dims d = ks*32 + g*8 + j  (mapping proven in R6/R7).
__global__ void prep_kernel(const float* __restrict__ E, float* __restrict__ ws) {
    int k = blockIdx.x * 256 + threadIdx.x;      // code
    float* e2 = ws;
    float* etf = (float*)((char*)ws + WS_ETF_OFF);
    unsigned short* ethF = (unsigned short*)((char*)ws + WS_ETH_OFF);
    unsigned short* etlF = (unsigned short*)((char*)ws + WS_ETL_OFF);

    const int tile = k >> 6, ct = (k >> 4) & 3, l15 = k & 15;
    float s = 0.f;
    #pragma unroll
    for (int d = 0; d < D; ++d) {
        float v = E[d * K + k];
        s = fmaf(v, v, s);
        etf[k * D + d] = v;
        unsigned short h = f2bf(v);
        unsigned short l = f2bf(v - bf2f(h));
        const int ks = d >> 5, g = (d >> 3) & 3, j = d & 7;
        const int slot = (((tile * 4 + ct) * 2 + ks) * 64 + g * 16 + l15) * 8 + j;
        ethF[slot] = h;
        etlF[slot] = l;
    }
    e2[k] = s;
}

// ---- exact rescore (bit-identical R1 chain); lane = wave lane 0..63 ----
__device__ __attribute__((noinline)) int rescore_token(
    const float* __restrict__ X, const float* __restrict__ E,
    const float* __restrict__ e2g, int tok, int lane)
{
    const float* xr = X + (size_t)tok * D;
    float bestv = 3.4e38f; int besti = 0;
    #pragma unroll 1
    for (int sb = 0; sb < 2; ++sb) {
        const int k0 = lane * 16 + sb * 8;
        float dot[8] = {0.f,0.f,0.f,0.f,0.f,0.f,0.f,0.f};
        #pragma unroll 1
        for (int db = 0; db < 4; ++db) {
            float4 xc0 = *reinterpret_cast<const float4*>(xr + db * 16 + 0);
            float4 xc1 = *reinterpret_cast<const float4*>(xr + db * 16 + 4);
            float4 xc2 = *reinterpret_cast<const float4*>(xr + db * 16 + 8);
            float4 xc3 = *reinterpret_cast<const float4*>(xr + db * 16 + 12);
            float xs[16] = {xc0.x,xc0.y,xc0.z,xc0.w, xc1.x,xc1.y,xc1.z,xc1.w,
                            xc2.x,xc2.y,xc2.z,xc2.w, xc3.x,xc3.y,xc3.z,xc3.w};
            #pragma unroll
            for (int dd = 0; dd < 16; ++dd) {           // d ascending
                const int d = db * 16 + dd;
                float4 e0 = *reinterpret_cast<const float4*>(E + (size_t)d * K + k0);
                float4 e1 = *reinterpret_cast<const float4*>(E + (size_t)d * K + k0 + 4);
                dot[0] = fmaf(xs[dd], e0.x, dot[0]); dot[1] = fmaf(xs[dd], e0.y, dot[1]);
                dot[2] = fmaf(xs[dd], e0.z, dot[2]); dot[3] = fmaf(xs[dd], e0.w, dot[3]);
                dot[4] = fmaf(xs[dd], e1.x, dot[4]); dot[5] = fmaf(xs[dd], e1.y, dot[5]);
                dot[6] = fmaf(xs[dd], e1.z, dot[6]); dot[7] = fmaf(xs[dd], e1.w, dot[7]);
            }
        }
        float4 ez0 = *reinterpret_cast<const float4*>(e2g + k0);
        float4 ez1 = *reinterpret_cast<const float4*>(e2g + k0 + 4);
        float ezs[8] = {ez0.x,ez0.y,ez0.z,ez0.w, ez1.x,ez1.y,ez1.z,ez1.w};
        #pragma unroll
        for (int j = 0; j < 8; ++j) {
            float dist = fmaf(-2.f, dot[j], ezs[j]);
            if (dist < bestv) { bestv = dist; besti = k0 + j; }
        }
    }
    #pragma unroll
    for (int mm = 1; mm <= 32; mm <<= 1) {
        float ob = __shfl_xor(bestv, mm, 64);
        int   oi = __shfl_xor(besti, mm, 64);
        bool take = (ob < bestv) || (ob == bestv && oi < besti);
        bestv = take ? ob : bestv;
        besti = take ? oi : besti;
    }
    return besti;
}

// ---- main: 4 waves/block (independent), 16 tokens/wave; no LDS, no barriers ----
__global__ __launch_bounds__(256, 2) void vq_mfma_kernel(
    const float* __restrict__ X,
    const float* __restrict__ E,
    const float* __restrict__ ws_f,
    float* __restrict__ qout,
    float* __restrict__ oneh,
    float* __restrict__ idxout)
{
    const int lane   = threadIdx.x & 63;
    const int wv     = threadIdx.x >> 6;          // wave 0..3
    const int lane15 = lane & 15;
    const int g      = lane >> 4;                 // 0..3
    const int tokbase = blockIdx.x * 64 + wv * 16;

    const float* e2g = ws_f;
    const float* etf = (const float*)((const char*)ws_f + WS_ETF_OFF);
    const bf16x8* ethF = (const bf16x8*)((const char*)ws_f + WS_ETH_OFF);
    const bf16x8* etlF = (const bf16x8*)((const char*)ws_f + WS_ETL_OFF);

    // A fragments (mapping proven in R6/R7)
    bf16x8 ah[2], al[2];
    {
        const float* xr = X + (size_t)(tokbase + lane15) * D + g * 8;
        #pragma unroll
        for (int ks = 0; ks < 2; ++ks) {
            float4 v0 = *reinterpret_cast<const float4*>(xr + ks * 32);
            float4 v1 = *reinterpret_cast<const float4*>(xr + ks * 32 + 4);
            float xv[8] = {v0.x,v0.y,v0.z,v0.w, v1.x,v1.y,v1.z,v1.w};
            #pragma unroll
            for (int j = 0; j < 8; ++j) {
                unsigned short h = f2bf(xv[j]);
                ah[ks][j] = (short)h;
                al[ks][j] = (short)f2bf(xv[j] - bf2f(h));
            }
        }
    }

    float bb[4] = {3.4e38f,3.4e38f,3.4e38f,3.4e38f};
    float b2[4] = {3.4e38f,3.4e38f,3.4e38f,3.4e38f};
    int   bi[4] = {0,0,0,0};

    #pragma unroll 1
    for (int tile = 0; tile < 16; ++tile) {
        #pragma unroll
        for (int ct = 0; ct < 4; ++ct) {
            const int code = tile * 64 + ct * 16 + lane15;
            f32x4 acc = {0.f, 0.f, 0.f, 0.f};
            #pragma unroll
            for (int ks = 0; ks < 2; ++ks) {
                // contiguous 1KB wave load: slot = (tile*8 + ct*2 + ks)*64 + lane
                const int slot = (tile * 8 + ct * 2 + ks) * 64 + lane;
                bf16x8 bh = ethF[slot];
                bf16x8 bl = etlF[slot];
                acc = __builtin_amdgcn_mfma_f32_16x16x32_bf16(ah[ks], bh, acc, 0, 0, 0);
                acc = __builtin_amdgcn_mfma_f32_16x16x32_bf16(ah[ks], bl, acc, 0, 0, 0);
                acc = __builtin_amdgcn_mfma_f32_16x16x32_bf16(al[ks], bh, acc, 0, 0, 0);
            }
            const float e2v = e2g[code];
            #pragma unroll
            for (int r = 0; r < 4; ++r) {   // C/D: col=lane15=code, row=g*4+r=token
                float dist = fmaf(-2.f, acc[r], e2v);
                b2[r] = fminf(b2[r], fmaxf(bb[r], dist));
                if (dist < bb[r]) { bb[r] = dist; bi[r] = code; }
            }
        }
    }

    // reduce best/best2 over the 16 lanes sharing each token row
    #pragma unroll
    for (int m = 1; m <= 8; m <<= 1) {
        #pragma unroll
        for (int r = 0; r < 4; ++r) {
            float ob = __shfl_xor(bb[r], m, 64);
            float o2 = __shfl_xor(b2[r], m, 64);
            int   oi = __shfl_xor(bi[r], m, 64);
            float nb2 = fminf(fminf(b2[r], o2), fmaxf(bb[r], ob));
            bool take = (ob < bb[r]) || (ob == bb[r] && oi < bi[r]);
            bb[r] = take ? ob : bb[r];
            bi[r] = take ? oi : bi[r];
            b2[r] = nb2;
        }
    }

    // margin-guarded exact rescore (tau = 0.125, proven R6/R7)
    #pragma unroll
    for (int r = 0; r < 4; ++r) {
        bool flag = (b2[r] - bb[r]) < 0.125f;
        unsigned long long m = __ballot(flag);
        if (m) {
            #pragma unroll
            for (int gg = 0; gg < 4; ++gg) {
                if ((m >> (gg * 16)) & 1ULL) {
                    int ei = rescore_token(X, E, e2g, tokbase + gg * 4 + r, lane);
                    if (g == gg) bi[r] = ei;
                }
            }
        }
    }

    // broadcast the 16 winning indices (compile-time indexed -> stays in VGPRs)
    int fi[16];
    #pragma unroll
    for (int t = 0; t < 16; ++t)
        fi[t] = __shfl(bi[t & 3], (t >> 2) * 16, 64);

    // qout (exact f32 codebook copy; STE x + (q - x)) + idxout
    #pragma unroll
    for (int t = 0; t < 16; ++t) {
        const size_t tok = (size_t)tokbase + t;
        float q = etf[(size_t)fi[t] * D + lane];
        float xv = X[tok * D + lane];
        qout[tok * D + lane] = xv + (q - xv);
        if (lane == t) idxout[tok] = (float)fi[t];
    }

    // one-hot: 16 rows x 1024 floats, value computed inline (branchless),
    // wave-private rows -> no ordering hazards, coalesced float4 stores
    {
        float4* ohb = reinterpret_cast<float4*>(oneh + (size_t)tokbase * K);
        #pragma unroll
        for (int i = 0; i < 64; ++i) {
            const int r  = i >> 2;                   // token row (compile-time)
            const int c4 = ((i & 3) * 64 + lane) * 4;
            const int id = fi[r];
            float4 v;
            v.x = (id == c4 + 0) ? 1.f : 0.f;
            v.y = (id == c4 + 1) ? 1.f : 0.f;
            v.z = (id == c4 + 2) ? 1.f : 0.f;
            v.w = (id == c4 + 3) ? 1.f : 0.f;
            ohb[i * 64 + lane] = v;
        }
    }
}

// ---- fallback (R1, proven) if workspace too small ----
__global__ __launch_bounds__(256, 2) void vq_fallback_kernel(
    const float* __restrict__ X, const float* __restrict__ E,
    float* __restrict__ qout, float* __restrict__ oneh, float* __restrict__ idxout)
{
    __shared__ float e2s[K];
    __shared__ int   idxs[256];
    const int tid = threadIdx.x;
    const int tok = blockIdx.x * 256 + tid;
    for (int k = tid; k < K; k += 256) {
        float s = 0.f;
        #pragma unroll
        for (int d = 0; d < D; ++d) { float v = E[d * K + k]; s = fmaf(v, v, s); }
        e2s[k] = s;
    }
    __syncthreads();
    float x[D];
    {
        const float* xp = X + (size_t)tok * D;
        #pragma unroll
        for (int j = 0; j < D / 4; ++j) {
            float4 v = *reinterpret_cast<const float4*>(xp + 4 * j);
            x[4*j+0]=v.x; x[4*j+1]=v.y; x[4*j+2]=v.z; x[4*j+3]=v.w;
        }
    }
    float best = 3.4e38f; int bidx = 0;
    for (int t0 = 0; t0 < K; t0 += 16) {
        float acc[16];
        #pragma unroll
        for (int j = 0; j < 16; ++j) acc[j] = 0.f;
        #pragma unroll
        for (int d = 0; d < D; ++d) {
            const float* ep = E + d * K + t0;
            #pragma unroll
            for (int j = 0; j < 16; ++j) acc[j] = fmaf(x[d], ep[j], acc[j]);
        }
        #pragma unroll
        for (int j = 0; j < 16; ++j) {
            float dist = fmaf(-2.f, acc[j], e2s[t0 + j]);
            if (dist < best) { best = dist; bidx = t0 + j; }
        }
    }
    idxs[tid] = bidx;
    {
        float q[D];
        const float* ec = E + bidx;
        #pragma unroll
        for (int d = 0; d < D; ++d) q[d] = ec[d * K];
        float* qp = qout + (size_t)tok * D;
        #pragma unroll
        for (int j = 0; j < D / 4; ++j) {
            float4 v;
            v.x = x[4*j+0] + (q[4*j+0] - x[4*j+0]);
            v.y = x[4*j+1] + (q[4*j+1] - x[4*j+1]);
            v.z = x[4*j+2] + (q[4*j+2] - x[4*j+2]);
            v.w = x[4*j+3] + (q[4*j+3] - x[4*j+3]);
            *reinterpret_cast<float4*>(qp + 4 * j) = v;
        }
    }
    idxout[tok] = (float)bidx;
    __syncthreads();
    {
        float4* base = reinterpret_cast<float4*>(oneh + (size_t)blockIdx.x * 256 * K);
        for (int i = tid; i < 256 * K / 4; i += 256) {
            int row = i >> 8, c4 = (i & 255) * 4, id = idxs[row];
            float4 v;
            v.x = (id == c4 + 0) ? 1.f : 0.f;
            v.y = (id == c4 + 1) ? 1.f : 0.f;
            v.z = (id == c4 + 2) ? 1.f : 0.f;
            v.w = (id == c4 + 3) ? 1.f : 0.f;
            base[i] = v;
        }
    }
}

extern "C" void kernel_launch(void* const* d_in, const int* in_sizes, int n_in,
                              void* d_out, int out_size, void* d_ws, size_t ws_size,
                              hipStream_t stream) {
    const float* X = (const float*)d_in[0];
    const float* E = (const float*)d_in[1];
    float* qout   = (float*)d_out;
    float* oneh   = qout + Q_ELEMS;
    float* idxout = oneh + OH_ELEMS;

    if (ws_size >= (size_t)WS_NEED) {
        float* ws = (float*)d_ws;
        prep_kernel<<<K / 256, 256, 0, stream>>>(E, ws);
        vq_mfma_kernel<<<NTOK / 64, 256, 0, stream>>>(X, E, ws, qout, oneh, idxout);
    } else {
        vq_fallback_kernel<<<NTOK / 256, 256, 0, stream>>>(X, E, qout, oneh, idxout);
    }
}